// Round 1
// 541.929 us; speedup vs baseline: 1.0423x; 1.0423x over previous
//
#include <hip/hip_runtime.h>
#include <math.h>

// Problem constants (from the reference file; RECORD_LEN is a module constant).
#define C_DIM 256
#define W_DIM 64
#define H_DIM 192
#define WH (W_DIM * H_DIM)          // 12288 spatial positions
#define NGROUPS 8
#define NCHUNK 4                    // C split into 4 chunks of 64 -> 4x the waves
#define CCHUNK (C_DIM / NCHUNK)     // 64 channels per chunk
#define NBLK (WH / 256)             // 48 blocks along n per (group, chunk)
#define TRI_TOTAL 68                // sum of L*(L+1)/2 over groups

// ---------------------------------------------------------------------------
// Kernel A: partial gram sums per 64-channel chunk.
//   ws[chunk][triBase[g]+idx][n] = sum_{c in chunk} x[l,c,n]*x[m,c,n]
// 1536 blocks (8 groups x 4 chunks x 48) = 24 waves/CU -> latency hidden.
// Each x element is read exactly once; stays cached in L3 for kernel B.
// ---------------------------------------------------------------------------
template <int L>
__device__ __forceinline__ void gram_partial_body(
    const float* __restrict__ xg,   // group base: x + off*C*WH
    float* __restrict__ wsg,        // ws + (chunk*TRI_TOTAL + triBase[g])*WH
    const int c0, const int n)
{
    constexpr int NTRI = L * (L + 1) / 2;
    float s[NTRI];
#pragma unroll
    for (int i = 0; i < NTRI; ++i) s[i] = 0.0f;

#pragma unroll 4
    for (int cc = 0; cc < CCHUNK; ++cc) {
        const int c = c0 + cc;
        float v[L];
#pragma unroll
        for (int l = 0; l < L; ++l)
            v[l] = xg[(size_t)(l * C_DIM + c) * WH + n];
        int idx = 0;
#pragma unroll
        for (int l = 0; l < L; ++l)
#pragma unroll
            for (int m = l; m < L; ++m)
                s[idx++] += v[l] * v[m];
    }

#pragma unroll
    for (int i = 0; i < NTRI; ++i)
        wsg[(size_t)i * WH + n] = s[i];
}

__global__ __launch_bounds__(256) void gram_kernel(
    const float* __restrict__ x,
    float* __restrict__ ws)
{
    const int b = blockIdx.x;
    const int g = b / (NCHUNK * NBLK);            // block-uniform
    const int rem = b - g * (NCHUNK * NBLK);
    const int chunk = rem / NBLK;
    const int bn = rem - chunk * NBLK;
    const int n = bn * 256 + threadIdx.x;
    const int c0 = chunk * CCHUNK;

    const int offs[NGROUPS]    = {0, 5, 8, 12, 14, 19, 22, 26};
    const int lens[NGROUPS]    = {5, 3, 4, 2, 5, 3, 4, 2};
    const int triBase[NGROUPS] = {0, 15, 21, 31, 34, 49, 55, 65};

    const float* xg = x + (size_t)offs[g] * C_DIM * WH;
    float* wsg = ws + (size_t)(chunk * TRI_TOTAL + triBase[g]) * WH;

    switch (lens[g]) {   // block-uniform branch -> no divergence
        case 5: gram_partial_body<5>(xg, wsg, c0, n); break;
        case 4: gram_partial_body<4>(xg, wsg, c0, n); break;
        case 3: gram_partial_body<3>(xg, wsg, c0, n); break;
        case 2: gram_partial_body<2>(xg, wsg, c0, n); break;
    }
}

// ---------------------------------------------------------------------------
// Kernel B: reduce the 4 partial grams, softmax row 0, context for the
// block's 64-channel chunk. Groups walked in REVERSE of kernel A's stream
// order so the first reads hit A's still-L3-resident tail. x loads and out
// stores are non-temporal: last-use data must not evict the unread groups.
// ---------------------------------------------------------------------------
template <int L, bool WRITE_ATTN>
__device__ __forceinline__ void ctx_body(
    const float* __restrict__ xg,
    const float* __restrict__ wsg,  // ws + triBase[g]*WH
    float* __restrict__ out,        // out0 + g*C*WH
    float* __restrict__ attn_out,   // (L, L, WH) or nullptr
    const int c0, const int n)
{
    constexpr int NTRI = L * (L + 1) / 2;

    // ---- Reduce partial grams ----
    float s[NTRI];
#pragma unroll
    for (int i = 0; i < NTRI; ++i) {
        float acc = 0.0f;
#pragma unroll
        for (int ch = 0; ch < NCHUNK; ++ch)
            acc += wsg[(size_t)(ch * TRI_TOTAL + i) * WH + n];
        s[i] = acc;
    }

    const float scale = 0.0625f;   // 1/sqrt(256)

    // ---- Softmax of row 0 (upper triangle row 0 == full row 0) ----
    float p0[L];
    float mx = -INFINITY;
#pragma unroll
    for (int m = 0; m < L; ++m) {
        p0[m] = s[m] * scale;
        mx = fmaxf(mx, p0[m]);
    }
    float sum = 0.0f;
#pragma unroll
    for (int m = 0; m < L; ++m) {
        p0[m] = __expf(p0[m] - mx);
        sum += p0[m];
    }
    const float inv = 1.0f / sum;
#pragma unroll
    for (int m = 0; m < L; ++m) p0[m] *= inv;

    // ---- Optional: full attention map (transpose(1,2,0): [l][m][n]) ----
    if constexpr (WRITE_ATTN) {
        float gm[L][L];
        int idx = 0;
#pragma unroll
        for (int l = 0; l < L; ++l)
#pragma unroll
            for (int m = l; m < L; ++m) {
                const float v = s[idx++] * scale;
                gm[l][m] = v;
                gm[m][l] = v;
            }
#pragma unroll
        for (int l = 0; l < L; ++l) {
            float mx2 = -INFINITY;
#pragma unroll
            for (int m = 0; m < L; ++m) mx2 = fmaxf(mx2, gm[l][m]);
            float e[L];
            float sm = 0.0f;
#pragma unroll
            for (int m = 0; m < L; ++m) {
                e[m] = __expf(gm[l][m] - mx2);
                sm += e[m];
            }
            const float iv = 1.0f / sm;
#pragma unroll
            for (int m = 0; m < L; ++m)
                attn_out[(size_t)(l * L + m) * WH + n] = e[m] * iv;
        }
    }

    // ---- Context for row 0, this chunk only; NT loads/stores ----
#pragma unroll 4
    for (int cc = 0; cc < CCHUNK; ++cc) {
        const int c = c0 + cc;
        float acc = 0.0f;
#pragma unroll
        for (int m = 0; m < L; ++m)
            acc += p0[m] * __builtin_nontemporal_load(
                              &xg[(size_t)(m * C_DIM + c) * WH + n]);
        __builtin_nontemporal_store(acc, &out[(size_t)c * WH + n]);
    }
}

__global__ __launch_bounds__(256) void ctx_kernel(
    const float* __restrict__ x,
    const float* __restrict__ ws,
    float* __restrict__ out0,
    float* __restrict__ attn)
{
    const int b = blockIdx.x;
    const int gi = b / (NCHUNK * NBLK);
    const int g = NGROUPS - 1 - gi;               // reverse group order (L3 reuse)
    const int rem = b - gi * (NCHUNK * NBLK);
    const int chunk = rem / NBLK;
    const int bn = rem - chunk * NBLK;
    const int n = bn * 256 + threadIdx.x;
    const int c0 = chunk * CCHUNK;

    const int offs[NGROUPS]    = {0, 5, 8, 12, 14, 19, 22, 26};
    const int lens[NGROUPS]    = {5, 3, 4, 2, 5, 3, 4, 2};
    const int triBase[NGROUPS] = {0, 15, 21, 31, 34, 49, 55, 65};

    const float* xg = x + (size_t)offs[g] * C_DIM * WH;
    const float* wsg = ws + (size_t)triBase[g] * WH;
    float* og = out0 + (size_t)g * C_DIM * WH;

    switch (lens[g]) {   // block-uniform branch -> no divergence
        case 5: ctx_body<5, false>(xg, wsg, og, nullptr, c0, n); break;
        case 4: ctx_body<4, false>(xg, wsg, og, nullptr, c0, n); break;
        case 3: ctx_body<3, false>(xg, wsg, og, nullptr, c0, n); break;
        case 2:
            if (g == NGROUPS - 1 && chunk == 0)
                ctx_body<2, true>(xg, wsg, og, attn, c0, n);
            else
                ctx_body<2, false>(xg, wsg, og, nullptr, c0, n);
            break;
    }
}

extern "C" void kernel_launch(void* const* d_in, const int* in_sizes, int n_in,
                              void* d_out, int out_size, void* d_ws, size_t ws_size,
                              hipStream_t stream) {
    const float* x = (const float*)d_in[0];
    float* out0 = (float*)d_out;                        // (8, C, W, H)
    float* attn = out0 + (size_t)NGROUPS * C_DIM * WH;  // (2, 2, W, H), last group
    float* ws = (float*)d_ws;                           // 4*68*WH floats = 13.4 MB

    const dim3 grid(NGROUPS * NCHUNK * NBLK);           // 1536 blocks
    const dim3 block(256);
    gram_kernel<<<grid, block, 0, stream>>>(x, ws);
    ctx_kernel<<<grid, block, 0, stream>>>(x, ws, out0, attn);
}

// Round 2
// 532.153 us; speedup vs baseline: 1.0615x; 1.0184x over previous
//
#include <hip/hip_runtime.h>
#include <math.h>

// Problem constants (from the reference file; RECORD_LEN is a module constant).
#define C_DIM 256
#define W_DIM 64
#define H_DIM 192
#define WH (W_DIM * H_DIM)          // 12288 spatial positions
#define NGROUPS 8
#define NCHUNK 4                    // C split across threads within a block
#define CCHUNK (C_DIM / NCHUNK)     // 64 channels per chunk-thread
#define NLOC 64                     // n positions per block
#define NBLK (WH / NLOC)            // 192 n-blocks per group
#define MAXTRI 15                   // L=5 -> 15 upper-triangle entries

// Fused single kernel, in-block C-split:
//   block = 256 threads = (4 chunks) x (64 n positions).
//   Pass 1: each thread -> partial gram over its 64 channels (coalesced,
//           wave = 64 consecutive n). Partials -> LDS, one barrier, reduce.
//   Softmax row 0 (redundant per chunk -- negligible ALU).
//   Pass 2: each thread -> context for its 64 channels at its n. Re-reads
//           the same x it read in pass 1 (L2/L3-hot, like the round-0 fused
//           kernel whose FETCH was exactly 1x input). NT loads/stores on
//           last-use data so the dying stream doesn't evict other groups.
// Grid = 8 groups x 192 = 1536 blocks = 6144 waves = 24 waves/CU (vs 6
// in the one-thread-per-n version that ran latency-bound at 2 TB/s).
template <int L, bool WRITE_ATTN>
__device__ __forceinline__ void att_body(
    const float* __restrict__ xg,   // group base: x + off*C*WH
    float* __restrict__ out,        // out0 + g*C*WH  (C, WH)
    float* __restrict__ attn_out,   // (L, L, WH) or nullptr
    float* __restrict__ lds,        // MAXTRI*256 floats
    const int n, const int chunk, const int nl)
{
    constexpr int NTRI = L * (L + 1) / 2;

    // ---- Pass 1: partial upper-triangle gram over this thread's chunk ----
    float s[NTRI];
#pragma unroll
    for (int i = 0; i < NTRI; ++i) s[i] = 0.0f;

    const int c0 = chunk * CCHUNK;
#pragma unroll 4
    for (int cc = 0; cc < CCHUNK; ++cc) {
        const int c = c0 + cc;
        float v[L];
#pragma unroll
        for (int l = 0; l < L; ++l)
            v[l] = xg[(size_t)(l * C_DIM + c) * WH + n];
        int idx = 0;
#pragma unroll
        for (int l = 0; l < L; ++l)
#pragma unroll
            for (int m = l; m < L; ++m)
                s[idx++] += v[l] * v[m];
    }

    // ---- Cross-chunk reduction through LDS (conflict-free: stride-1) ----
#pragma unroll
    for (int i = 0; i < NTRI; ++i)
        lds[i * 256 + chunk * NLOC + nl] = s[i];
    __syncthreads();

    float sf[NTRI];
#pragma unroll
    for (int i = 0; i < NTRI; ++i) {
        float a = lds[i * 256 + nl];
#pragma unroll
        for (int ch = 1; ch < NCHUNK; ++ch)
            a += lds[i * 256 + ch * NLOC + nl];
        sf[i] = a;
    }

    const float scale = 0.0625f;   // 1/sqrt(256)

    // ---- Softmax of row 0 (upper triangle row 0 == full row 0) ----
    float p0[L];
    float mx = -INFINITY;
#pragma unroll
    for (int m = 0; m < L; ++m) {
        p0[m] = sf[m] * scale;
        mx = fmaxf(mx, p0[m]);
    }
    float sum = 0.0f;
#pragma unroll
    for (int m = 0; m < L; ++m) {
        p0[m] = __expf(p0[m] - mx);
        sum += p0[m];
    }
    const float inv = 1.0f / sum;
#pragma unroll
    for (int m = 0; m < L; ++m) p0[m] *= inv;

    // ---- Optional: full attention map (transpose(1,2,0): [l][m][n]) ----
    // Only the chunk-0 wave writes (wave-uniform predicate, no divergence
    // inside a wave); it covers every n of the block.
    if constexpr (WRITE_ATTN) {
        if (chunk == 0) {
            float gm[L][L];
            int idx = 0;
#pragma unroll
            for (int l = 0; l < L; ++l)
#pragma unroll
                for (int m = l; m < L; ++m) {
                    const float v = sf[idx++] * scale;
                    gm[l][m] = v;
                    gm[m][l] = v;
                }
#pragma unroll
            for (int l = 0; l < L; ++l) {
                float mx2 = -INFINITY;
#pragma unroll
                for (int m = 0; m < L; ++m) mx2 = fmaxf(mx2, gm[l][m]);
                float e[L];
                float sm = 0.0f;
#pragma unroll
                for (int m = 0; m < L; ++m) {
                    e[m] = __expf(gm[l][m] - mx2);
                    sm += e[m];
                }
                const float iv = 1.0f / sm;
#pragma unroll
                for (int m = 0; m < L; ++m)
                    __builtin_nontemporal_store(
                        e[m] * iv, &attn_out[(size_t)(l * L + m) * WH + n]);
            }
        }
    }

    // ---- Pass 2: context for row 0, this thread's 64 channels ----
#pragma unroll 4
    for (int cc = 0; cc < CCHUNK; ++cc) {
        const int c = c0 + cc;
        float acc = 0.0f;
#pragma unroll
        for (int m = 0; m < L; ++m)
            acc += p0[m] * __builtin_nontemporal_load(
                              &xg[(size_t)(m * C_DIM + c) * WH + n]);
        __builtin_nontemporal_store(acc, &out[(size_t)c * WH + n]);
    }
}

__global__ __launch_bounds__(256) void att_fused_kernel(
    const float* __restrict__ x,
    float* __restrict__ out0,
    float* __restrict__ attn)
{
    __shared__ float lds[MAXTRI * 256];

    const int b = blockIdx.x;
    const int g = b / NBLK;                        // block-uniform
    const int bn = b - g * NBLK;
    const int chunk = threadIdx.x >> 6;            // wave index = chunk
    const int nl = threadIdx.x & 63;
    const int n = bn * NLOC + nl;

    const int offs[NGROUPS] = {0, 5, 8, 12, 14, 19, 22, 26};
    const int lens[NGROUPS] = {5, 3, 4, 2, 5, 3, 4, 2};

    const float* xg = x + (size_t)offs[g] * C_DIM * WH;
    float* og = out0 + (size_t)g * C_DIM * WH;

    switch (lens[g]) {   // block-uniform branch -> no divergence
        case 5: att_body<5, false>(xg, og, nullptr, lds, n, chunk, nl); break;
        case 4: att_body<4, false>(xg, og, nullptr, lds, n, chunk, nl); break;
        case 3: att_body<3, false>(xg, og, nullptr, lds, n, chunk, nl); break;
        case 2:
            if (g == NGROUPS - 1)
                att_body<2, true>(xg, og, attn, lds, n, chunk, nl);
            else
                att_body<2, false>(xg, og, nullptr, lds, n, chunk, nl);
            break;
    }
}

extern "C" void kernel_launch(void* const* d_in, const int* in_sizes, int n_in,
                              void* d_out, int out_size, void* d_ws, size_t ws_size,
                              hipStream_t stream) {
    const float* x = (const float*)d_in[0];
    float* out0 = (float*)d_out;                        // (8, C, W, H)
    float* attn = out0 + (size_t)NGROUPS * C_DIM * WH;  // (2, 2, W, H), last group

    const dim3 grid(NGROUPS * NBLK);               // 1536 blocks
    const dim3 block(256);
    att_fused_kernel<<<grid, block, 0, stream>>>(x, out0, attn);
}

// Round 3
// 501.196 us; speedup vs baseline: 1.1270x; 1.0618x over previous
//
#include <hip/hip_runtime.h>
#include <math.h>

// Problem constants (from the reference file; RECORD_LEN is a module constant).
#define C_DIM 256
#define W_DIM 64
#define H_DIM 192
#define WH (W_DIM * H_DIM)          // 12288 spatial positions
#define NGROUPS 8
#define NCHUNK 16                   // channel chunks per block (one per thread-col)
#define CCH (C_DIM / NCHUNK)        // 16 channels per thread
#define NLOC 32                     // n positions per block
#define NBLK (WH / NLOC)            // 384 n-blocks per group
#define BLOCK 512                   // 16 chunks x 32 n

// Read-x-ONCE fused kernel.
//   Each thread owns (one n, 16 channels, all L records): v[L][16] in
//   registers (80 VGPRs at L=5). Row-0 gram partials (only row 0 of the
//   score matrix feeds the output; full LxL map needed only for the last
//   group, L=2 -> 3 tri entries) are reduced across the 16 chunks through
//   10 KB LDS with ONE barrier. Context is then computed entirely from
//   registers -> x is fetched from HBM exactly once (the round-2 version
//   re-read x in pass 2 and thrashed L3: 8 concurrent groups = 352 MB
//   working set > 256 MB L3 -> FETCH was ~2x input).
//   Wave = 2 chunks x 32 consecutive n -> every load/store is 2 aligned
//   128B segments. Grid 8*384=3072 blocks = 24576 waves; launch_bounds
//   (512,3) keeps VGPR<=168 (no spill of v[5][16]) at ~12 waves/CU.
template <int L, bool WRITE_ATTN>
__device__ __forceinline__ void att_body(
    const float* __restrict__ xg,   // group base: x + off*C*WH
    float* __restrict__ out,        // out0 + g*C*WH  (C, WH)
    float* __restrict__ attn_out,   // (L, L, WH) or nullptr
    float* __restrict__ lds,        // 5*BLOCK floats
    const int n, const int chunk, const int nl)
{
    constexpr int NTRI = L * (L + 1) / 2;
    constexpr int NACC = WRITE_ATTN ? NTRI : L;   // row-0 only unless attn map
    static_assert(NACC <= 5, "LDS sized for <=5 accumulators");

    const int c0 = chunk * CCH;

    // ---- Load this thread's slab of x into registers (read-once) ----
    float v[L][CCH];
#pragma unroll
    for (int cc = 0; cc < CCH; ++cc)
#pragma unroll
        for (int l = 0; l < L; ++l)
            v[l][cc] = xg[(size_t)(l * C_DIM + c0 + cc) * WH + n];

    // ---- Partial gram (row 0, or full tri for the attn-map group) ----
    float s[NACC];
#pragma unroll
    for (int i = 0; i < NACC; ++i) s[i] = 0.0f;

    if constexpr (WRITE_ATTN) {
#pragma unroll
        for (int cc = 0; cc < CCH; ++cc) {
            int idx = 0;
#pragma unroll
            for (int l = 0; l < L; ++l)
#pragma unroll
                for (int m = l; m < L; ++m)
                    s[idx++] += v[l][cc] * v[m][cc];
        }
    } else {
#pragma unroll
        for (int cc = 0; cc < CCH; ++cc)
#pragma unroll
            for (int m = 0; m < L; ++m)
                s[m] += v[0][cc] * v[m][cc];
    }

    // ---- Cross-chunk reduction through LDS (conflict-free both ways) ----
#pragma unroll
    for (int i = 0; i < NACC; ++i)
        lds[i * BLOCK + chunk * NLOC + nl] = s[i];
    __syncthreads();

    float sf[NACC];
#pragma unroll
    for (int i = 0; i < NACC; ++i) {
        float a = 0.0f;
#pragma unroll
        for (int ch = 0; ch < NCHUNK; ++ch)
            a += lds[i * BLOCK + ch * NLOC + nl];
        sf[i] = a;
    }

    const float scale = 0.0625f;   // 1/sqrt(256)

    // ---- Softmax of row 0 (first L accumulators are (0,m)) ----
    float p0[L];
    float mx = -INFINITY;
#pragma unroll
    for (int m = 0; m < L; ++m) {
        p0[m] = sf[m] * scale;
        mx = fmaxf(mx, p0[m]);
    }
    float sum = 0.0f;
#pragma unroll
    for (int m = 0; m < L; ++m) {
        p0[m] = __expf(p0[m] - mx);
        sum += p0[m];
    }
    const float inv = 1.0f / sum;
#pragma unroll
    for (int m = 0; m < L; ++m) p0[m] *= inv;

    // ---- Optional full attention map: chunk r (< L) writes row r ----
    if constexpr (WRITE_ATTN) {
        if (chunk < L) {
            const int r = chunk;
            float row[L];
#pragma unroll
            for (int m = 0; m < L; ++m) {
                const int lo = (r < m) ? r : m;
                const int hi = (r < m) ? m : r;
                const int idx = lo * L - lo * (lo - 1) / 2 + (hi - lo);
                row[m] = sf[idx] * scale;
            }
            float mx2 = -INFINITY;
#pragma unroll
            for (int m = 0; m < L; ++m) mx2 = fmaxf(mx2, row[m]);
            float e[L];
            float sm = 0.0f;
#pragma unroll
            for (int m = 0; m < L; ++m) {
                e[m] = __expf(row[m] - mx2);
                sm += e[m];
            }
            const float iv = 1.0f / sm;
#pragma unroll
            for (int m = 0; m < L; ++m)
                __builtin_nontemporal_store(
                    e[m] * iv, &attn_out[(size_t)(r * L + m) * WH + n]);
        }
    }

    // ---- Context for row 0 from REGISTERS (no x re-read), stream out ----
#pragma unroll
    for (int cc = 0; cc < CCH; ++cc) {
        float acc = 0.0f;
#pragma unroll
        for (int m = 0; m < L; ++m)
            acc += p0[m] * v[m][cc];
        __builtin_nontemporal_store(acc, &out[(size_t)(c0 + cc) * WH + n]);
    }
}

__global__ __launch_bounds__(BLOCK, 3) void att_fused_kernel(
    const float* __restrict__ x,
    float* __restrict__ out0,
    float* __restrict__ attn)
{
    __shared__ float lds[5 * BLOCK];

    const int b = blockIdx.x;
    const int g = b / NBLK;                        // block-uniform
    const int bn = b - g * NBLK;
    const int chunk = threadIdx.x >> 5;            // 0..15 (2 chunks per wave)
    const int nl = threadIdx.x & 31;
    const int n = bn * NLOC + nl;

    const int offs[NGROUPS] = {0, 5, 8, 12, 14, 19, 22, 26};
    const int lens[NGROUPS] = {5, 3, 4, 2, 5, 3, 4, 2};

    const float* xg = x + (size_t)offs[g] * C_DIM * WH;
    float* og = out0 + (size_t)g * C_DIM * WH;

    switch (lens[g]) {   // block-uniform branch -> no divergence
        case 5: att_body<5, false>(xg, og, nullptr, lds, n, chunk, nl); break;
        case 4: att_body<4, false>(xg, og, nullptr, lds, n, chunk, nl); break;
        case 3: att_body<3, false>(xg, og, nullptr, lds, n, chunk, nl); break;
        case 2:
            if (g == NGROUPS - 1)
                att_body<2, true>(xg, og, attn, lds, n, chunk, nl);
            else
                att_body<2, false>(xg, og, nullptr, lds, n, chunk, nl);
            break;
    }
}

extern "C" void kernel_launch(void* const* d_in, const int* in_sizes, int n_in,
                              void* d_out, int out_size, void* d_ws, size_t ws_size,
                              hipStream_t stream) {
    const float* x = (const float*)d_in[0];
    float* out0 = (float*)d_out;                        // (8, C, W, H)
    float* attn = out0 + (size_t)NGROUPS * C_DIM * WH;  // (2, 2, W, H), last group

    const dim3 grid(NGROUPS * NBLK);               // 3072 blocks
    const dim3 block(BLOCK);
    att_fused_kernel<<<grid, block, 0, stream>>>(x, out0, attn);
}

// Round 4
// 492.644 us; speedup vs baseline: 1.1466x; 1.0174x over previous
//
#include <hip/hip_runtime.h>
#include <math.h>

// Problem constants (from the reference file; RECORD_LEN is a module constant).
#define C_DIM 256
#define W_DIM 64
#define H_DIM 192
#define WH (W_DIM * H_DIM)          // 12288 spatial positions
#define WH4 (WH / 4)                // 3072 float4-quads along n
#define NGROUPS 8
#define NLOC 32                     // n per block: exactly one 128B line per (l,c)
#define NQUAD (NLOC / 4)            // 8 quads per block
#define NCHUNK 128                  // channel chunks per block
#define CCH 2                       // channels per thread
#define BLOCK 1024                  // 128 chunks x 8 quads = 16 waves
#define NBLK (WH / NLOC)            // 384 n-blocks per group

typedef float v4 __attribute__((ext_vector_type(4)));

__device__ __forceinline__ v4 v4_max(v4 a, v4 b) {
    v4 r;
    r[0] = fmaxf(a[0], b[0]); r[1] = fmaxf(a[1], b[1]);
    r[2] = fmaxf(a[2], b[2]); r[3] = fmaxf(a[3], b[3]);
    return r;
}
__device__ __forceinline__ v4 v4_exp(v4 a) {
    v4 r;
    r[0] = __expf(a[0]); r[1] = __expf(a[1]);
    r[2] = __expf(a[2]); r[3] = __expf(a[3]);
    return r;
}

// Read-x-ONCE, dwordx4, low-pressure fused kernel.
//   Thread owns (4 consecutive n, 2 channels, all L records): v[L][2] float4
//   = 40 VGPRs at L=5 (R3 held 80 floats as 80 SCALAR loads -> spill /
//   serialized batches; this is the theory for R3's 2.9 TB/s effective BW).
//   Wave = 8 chunks x 8 quads: every global load/store is 8 full 128-B
//   lines (1 KB/instr). Block covers 32 n -> each HBM line is consumed
//   entirely within one block (no cross-block line sharing -> FETCH = 1x).
//   Chunk reduction: 3-round shfl_xor butterfly (8 chunks in-wave), then
//   16 wave-partials through 10 KB LDS, ONE barrier. Softmax + context
//   entirely from registers; all global accesses non-temporal (zero reuse).
template <int L, bool WRITE_ATTN>
__device__ __forceinline__ void att_body(
    const float* __restrict__ xg,   // group base: x + off*C*WH
    float* __restrict__ out,        // out0 + g*C*WH  (C, WH)
    float* __restrict__ attn_out,   // (L, L, WH) or nullptr
    v4* __restrict__ lds,           // 5*16*NQUAD v4s = 10 KB
    const int n4, const int chunk, const int quad, const int wave)
{
    constexpr int NTRI = L * (L + 1) / 2;
    constexpr int NACC = WRITE_ATTN ? NTRI : L;   // row-0 only unless attn map
    static_assert(NACC <= 5, "LDS sized for <=5 accumulators");

    const int c0 = chunk * CCH;
    const v4* xg4 = reinterpret_cast<const v4*>(xg);

    // ---- Load this thread's slab of x (read-once, dwordx4, NT) ----
    v4 v[L][CCH];
#pragma unroll
    for (int cc = 0; cc < CCH; ++cc)
#pragma unroll
        for (int l = 0; l < L; ++l)
            v[l][cc] = __builtin_nontemporal_load(
                &xg4[(size_t)(l * C_DIM + c0 + cc) * WH4 + n4]);

    // ---- Partial gram over this thread's 2 channels ----
    v4 s[NACC];
#pragma unroll
    for (int i = 0; i < NACC; ++i) s[i] = (v4)0.0f;

    if constexpr (WRITE_ATTN) {
#pragma unroll
        for (int cc = 0; cc < CCH; ++cc) {
            int idx = 0;
#pragma unroll
            for (int l = 0; l < L; ++l)
#pragma unroll
                for (int m = l; m < L; ++m)
                    s[idx++] += v[l][cc] * v[m][cc];
        }
    } else {
#pragma unroll
        for (int cc = 0; cc < CCH; ++cc)
#pragma unroll
            for (int m = 0; m < L; ++m)
                s[m] += v[0][cc] * v[m][cc];
    }

    // ---- In-wave butterfly over the 8 chunks of this wave (lane bits 3..5) ----
#pragma unroll
    for (int k = 8; k < 64; k <<= 1) {
#pragma unroll
        for (int i = 0; i < NACC; ++i) {
            v4 t;
#pragma unroll
            for (int j = 0; j < 4; ++j)
                t[j] = __shfl_xor(s[i][j], k);
            s[i] += t;
        }
    }

    // ---- Stage the 16 wave-partials in LDS (lanes 0..7 = quads 0..7) ----
    if ((threadIdx.x & 63) < 8) {
#pragma unroll
        for (int i = 0; i < NACC; ++i)
            lds[(i * 16 + wave) * NQUAD + quad] = s[i];
    }
    __syncthreads();

    // ---- Final 16-way sum (8 distinct addrs/wave -> broadcast, no conflict) ----
    v4 sf[NACC];
#pragma unroll
    for (int i = 0; i < NACC; ++i) {
        v4 a = lds[(i * 16 + 0) * NQUAD + quad];
#pragma unroll
        for (int w = 1; w < 16; ++w)
            a += lds[(i * 16 + w) * NQUAD + quad];
        sf[i] = a;
    }

    const float scale = 0.0625f;   // 1/sqrt(256)

    // ---- Softmax of row 0 (first L accumulators are (0,m)), 4 n at once ----
    v4 p0[L];
    v4 mx = (v4)(-INFINITY);
#pragma unroll
    for (int m = 0; m < L; ++m) {
        p0[m] = sf[m] * scale;
        mx = v4_max(mx, p0[m]);
    }
    v4 sum = (v4)0.0f;
#pragma unroll
    for (int m = 0; m < L; ++m) {
        p0[m] = v4_exp(p0[m] - mx);
        sum += p0[m];
    }
    v4 inv;
#pragma unroll
    for (int j = 0; j < 4; ++j) inv[j] = 1.0f / sum[j];
#pragma unroll
    for (int m = 0; m < L; ++m) p0[m] *= inv;

    // ---- Optional full attention map: chunk r (< L) writes row r ----
    if constexpr (WRITE_ATTN) {
        if (chunk < L) {
            const int r = chunk;
            v4 row[L];
            v4 mx2 = (v4)(-INFINITY);
#pragma unroll
            for (int m = 0; m < L; ++m) {
                const int lo = (r < m) ? r : m;
                const int hi = (r < m) ? m : r;
                const int idx = lo * L - lo * (lo - 1) / 2 + (hi - lo);
                row[m] = sf[idx] * scale;
                mx2 = v4_max(mx2, row[m]);
            }
            v4 sm = (v4)0.0f;
            v4 e[L];
#pragma unroll
            for (int m = 0; m < L; ++m) {
                e[m] = v4_exp(row[m] - mx2);
                sm += e[m];
            }
            v4 iv;
#pragma unroll
            for (int j = 0; j < 4; ++j) iv[j] = 1.0f / sm[j];
            v4* ao4 = reinterpret_cast<v4*>(attn_out);
#pragma unroll
            for (int m = 0; m < L; ++m)
                __builtin_nontemporal_store(
                    e[m] * iv, &ao4[(size_t)(r * L + m) * WH4 + n4]);
        }
    }

    // ---- Context for row 0 from REGISTERS, NT dwordx4 stream out ----
    v4* out4 = reinterpret_cast<v4*>(out);
#pragma unroll
    for (int cc = 0; cc < CCH; ++cc) {
        v4 acc = (v4)0.0f;
#pragma unroll
        for (int m = 0; m < L; ++m)
            acc += p0[m] * v[m][cc];
        __builtin_nontemporal_store(acc, &out4[(size_t)(c0 + cc) * WH4 + n4]);
    }
}

__global__ __launch_bounds__(BLOCK, 4) void att_fused_kernel(
    const float* __restrict__ x,
    float* __restrict__ out0,
    float* __restrict__ attn)
{
    __shared__ v4 lds[5 * 16 * NQUAD];             // 10 KB

    const int b = blockIdx.x;
    const int g = b / NBLK;                        // block-uniform
    const int bn = b - g * NBLK;
    const int chunk = threadIdx.x >> 3;            // 0..127
    const int quad = threadIdx.x & 7;              // 0..7
    const int wave = threadIdx.x >> 6;             // 0..15
    const int n4 = bn * NQUAD + quad;              // float4 index along n

    const int offs[NGROUPS] = {0, 5, 8, 12, 14, 19, 22, 26};
    const int lens[NGROUPS] = {5, 3, 4, 2, 5, 3, 4, 2};

    const float* xg = x + (size_t)offs[g] * C_DIM * WH;
    float* og = out0 + (size_t)g * C_DIM * WH;

    switch (lens[g]) {   // block-uniform branch -> no divergence
        case 5: att_body<5, false>(xg, og, nullptr, lds, n4, chunk, quad, wave); break;
        case 4: att_body<4, false>(xg, og, nullptr, lds, n4, chunk, quad, wave); break;
        case 3: att_body<3, false>(xg, og, nullptr, lds, n4, chunk, quad, wave); break;
        case 2:
            if (g == NGROUPS - 1)
                att_body<2, true>(xg, og, attn, lds, n4, chunk, quad, wave);
            else
                att_body<2, false>(xg, og, nullptr, lds, n4, chunk, quad, wave);
            break;
    }
}

extern "C" void kernel_launch(void* const* d_in, const int* in_sizes, int n_in,
                              void* d_out, int out_size, void* d_ws, size_t ws_size,
                              hipStream_t stream) {
    const float* x = (const float*)d_in[0];
    float* out0 = (float*)d_out;                        // (8, C, W, H)
    float* attn = out0 + (size_t)NGROUPS * C_DIM * WH;  // (2, 2, W, H), last group

    const dim3 grid(NGROUPS * NBLK);               // 3072 blocks
    const dim3 block(BLOCK);
    att_fused_kernel<<<grid, block, 0, stream>>>(x, out0, attn);
}